// Round 1
// baseline (2811.836 us; speedup 1.0000x reference)
//
#include <hip/hip_runtime.h>

#define BB 512
#define SS 256
#define HH 128
#define NC 10

typedef float v2f __attribute__((ext_vector_type(2)));

// acc + (give from lane selected by DPP ctrl)
template<int CTRL>
__device__ __forceinline__ float dppadd(float acc, float give) {
    int t = __builtin_amdgcn_update_dpp(0, __float_as_int(give), CTRL, 0xF, 0xF, true);
    return acc + __int_as_float(t);
}

// cndmask-free reduce-scatter over the 16-lane group.
// Input v[8] in permuted slot order (slot i = column 8j + (i^(r&7))).
// Returns full sum for column 8j + (r&7); copies at lanes r and r^8.
__device__ __forceinline__ float red_scatter(const float v[8], int r) {
    float s0 = dppadd<0xB1>(v[0], v[1]);    // xor1
    float s2 = dppadd<0xB1>(v[2], v[3]);
    float s4 = dppadd<0xB1>(v[4], v[5]);
    float s6 = dppadd<0xB1>(v[6], v[7]);
    s0 = dppadd<0x4E>(s0, s2);              // xor2
    s4 = dppadd<0x4E>(s4, s6);
    {   // xor4 via row_ror 4 / 12
        int t1 = __builtin_amdgcn_update_dpp(0, __float_as_int(s4), 0x124, 0xF, 0xF, true);
        int t2 = __builtin_amdgcn_update_dpp(0, __float_as_int(s4), 0x12C, 0xF, 0xF, true);
        s0 += __int_as_float((r & 4) ? t2 : t1);
    }
    s0 = dppadd<0x128>(s0, s0);             // xor8 (row_ror:8)
    return s0;
}

// =====================================================================
// proj_k: out[m][j] = sum_d A[m][d] * W[j][d]   (NO bias — scan adds it)
// Layer 0 input projection only (K=28).
// =====================================================================
template<int K>
__global__ __launch_bounds__(256, 1)
void proj_k(const float* __restrict__ A, const float* __restrict__ W,
            float* __restrict__ out)
{
    constexpr int AS = ((K + 31) / 32) * 32 + 4;
    constexpr int KQ = K / 4;
    constexpr int KCW = (K < 32) ? K : 32;
    constexpr int WQ = KCW / 4;
    const int tid = threadIdx.x;
    const int tx = tid & 15;
    const int ty = tid >> 4;
    const size_t m0 = (size_t)blockIdx.x * 64;

    __shared__ float Arm[64 * AS];
    __shared__ float Wst[128 * 36];

    for (int idx = tid; idx < 64 * KQ; idx += 256) {
        const int row = idx / KQ, kq = idx % KQ;
        const float4 v = *(const float4*)(A + (m0 + row) * K + 4 * kq);
        *(float4*)(&Arm[row * AS + 4 * kq]) = v;
    }

    float acc[4][8];
    #pragma unroll
    for (int c = 0; c < 8; ++c)
        #pragma unroll
        for (int r = 0; r < 4; ++r) acc[r][c] = 0.f;

    #pragma unroll 1
    for (int kc = 0; kc < K; kc += KCW) {
        __syncthreads();
        for (int idx = tid; idx < 128 * WQ; idx += 256) {
            const int col = idx / WQ, q = idx % WQ;
            const float4 v = *(const float4*)(W + (size_t)col * K + kc + 4 * q);
            *(float4*)(&Wst[col * 36 + 4 * q]) = v;
        }
        __syncthreads();
        #pragma unroll 2
        for (int q = 0; q < WQ; ++q) {
            float4 av[4];
            #pragma unroll
            for (int r = 0; r < 4; ++r)
                av[r] = *(const float4*)(&Arm[(ty + 16 * r) * AS + kc + 4 * q]);
            #pragma unroll
            for (int c = 0; c < 8; ++c) {
                const float4 wv = *(const float4*)(&Wst[(tx + 16 * c) * 36 + 4 * q]);
                #pragma unroll
                for (int r = 0; r < 4; ++r)
                    acc[r][c] += av[r].x * wv.x + av[r].y * wv.y
                               + av[r].z * wv.z + av[r].w * wv.w;
            }
        }
    }

    #pragma unroll
    for (int r = 0; r < 4; ++r)
        #pragma unroll
        for (int c = 0; c < 8; ++c)
            out[(m0 + ty + 16 * r) * HH + tx + 16 * c] = acc[r][c];
}

// =====================================================================
// fused_scan: all 4 layers wavefront-pipelined in ONE block per batch
// element. 1024 threads = 4 groups x 256; group l runs layer l with a
// pipeline skew of 2 wavefront steps (proj of h(s-1) is produced one
// local step late, exactly as the old scan_k did). Inter-layer xw goes
// through a depth-2 LDS ring instead of a 64 MB global round-trip.
// Per-group step body is the proven scan_k body:
//   h_s = tanh(bias + xw_l[s] + h_{s-1} @ W_hh^T)
//   (l<3) xw_{l+1}[s-1] = h_{s-1} @ W_ih_{l+1}^T   (bias-free)
// Schedule: group l runs local step s at wavefront step T = s + 2l.
//   producer writes xw(s-1) -> ring slot (s-1)&1 during T
//   consumer reads  xw(s)   <- ring slot  s&1     during T+... (1 step later)
// Total wavefront steps: 255 + 6 (l=3 last h) + epilogue projs = 262.
// =====================================================================
__global__ __launch_bounds__(1024, 1)
void fused_scan(const float* __restrict__ buf,      // layer-0 xw (B,S,H), read-only
                float* __restrict__ hfin,
                const float* __restrict__ w_hh0, const float* __restrict__ w_hh123,
                const float* __restrict__ w_ih123,
                const float* __restrict__ b_ih0, const float* __restrict__ b_hh0,
                const float* __restrict__ b_ih123, const float* __restrict__ b_hh123)
{
    const int b    = blockIdx.x;
    const int tid  = threadIdx.x;
    const int l    = tid >> 8;           // layer group 0..3 (4 waves each)
    const int t256 = tid & 255;
    const int j  = t256 >> 4;            // col group: cols 8j..8j+7
    const int r  = t256 & 15;            // k-chunk [8r, 8r+8)
    const int g7 = r & 7;
    const int cc  = 8 * j + g7;          // column this lane finalizes
    const int wsw = 12 * j + g7;         // its swizzled LDS word

    const float* whh = (l == 0) ? w_hh0 : w_hh123 + (size_t)(l - 1) * HH * HH;
    const float* wih = w_ih123 + (size_t)l * HH * HH;  // feeds layer l+1 (l<3)
    const float bias = ((l == 0) ? b_ih0[cc] : b_ih123[(l - 1) * HH + cc])
                     + ((l == 0) ? b_hh0[cc] : b_hh123[(l - 1) * HH + cc]);

    // permuted weights: slot i = column 8j + (i^g7), k-pair p
    v2f wh[8][4], wi[8][4];
    #pragma unroll
    for (int i = 0; i < 8; ++i) {
        const v2f* p = (const v2f*)(whh + (size_t)(8 * j + (i ^ g7)) * HH + 8 * r);
        wh[i][0] = p[0]; wh[i][1] = p[1]; wh[i][2] = p[2]; wh[i][3] = p[3];
    }
    if (l < 3) {
        #pragma unroll
        for (int i = 0; i < 8; ++i) {
            const v2f* p = (const v2f*)(wih + (size_t)(8 * j + (i ^ g7)) * HH + 8 * r);
            wi[i][0] = p[0]; wi[i][1] = p[1]; wi[i][2] = p[2]; wi[i][3] = p[3];
        }
    }

    __shared__ float hsw[4][2][192];     // per-layer h dbuf, word 12*(k>>3)+(k&7)
    __shared__ float xwr[3][2][HH];      // inter-layer xw ring (depth 2)
    __shared__ float xwl[2][8][HH];      // layer-0 global staging (8-step chunks)

    if (t256 < 192) hsw[l][0][t256] = 0.f;

    const float* row = buf + (size_t)b * SS * HH;
    const int t   = t256 >> 5;           // staging: step-in-chunk
    const int pos = (t256 & 31) * 4;     // staging: column (float4)
    if (l == 0) {                        // stage layer-0 xw for steps 0..7
        const float4 v = *(const float4*)(row + (size_t)t * HH + pos);
        *(float4*)(&xwl[0][t][pos]) = v;
    }
    __syncthreads();

    const int smax = (l < 3) ? SS : SS - 1;   // l<3 get an epilogue-proj step
    for (int T = 0; T < SS + 6; ++T) {
        const int s = T - 2 * l;              // group-local step
        if (s >= 0 && s <= smax) {            // wave-uniform guard
            const int rb = s & 1;
            // h_{s-1} fragments (shared by recurrence and projection)
            const v2f* hb = (const v2f*)&hsw[l][rb][12 * r];
            const v2f hp0 = hb[0], hp1 = hb[1], hp2 = hb[2], hp3 = hb[3];

            bool do_stage = false;
            float4 stg;
            int cb = 0;

            if (s < SS) {
                float myxw;
                if (l == 0) {
                    const int ph = s & 7;
                    cb = (s >> 3) & 1;
                    do_stage = (ph == 0) && (s + 8 < SS);
                    if (do_stage)
                        stg = *(const float4*)(row + (size_t)(s + 8 + t) * HH + pos);
                    myxw = xwl[cb][ph][cc] + bias;
                } else {
                    myxw = xwr[l - 1][rb][cc] + bias;   // 2-way broadcast read
                }

                // recurrence MAC (critical path)
                float v[8];
                #pragma unroll
                for (int i = 0; i < 8; ++i) {
                    v2f a = hp0 * wh[i][0];
                    a += hp1 * wh[i][1];
                    a += hp2 * wh[i][2];
                    a += hp3 * wh[i][3];
                    v[i] = a.x + a.y;
                }
                const float z = red_scatter(v, r) + myxw;
                const float e = __expf(2.f * z);
                const float hnew = 1.f - 2.f * __builtin_amdgcn_rcpf(1.f + e); // tanh
                if (r < 8) hsw[l][rb ^ 1][wsw] = hnew;
            }

            // projection of h_{s-1} into layer l+1's xw ring (latency-tolerant)
            if (l < 3 && s > 0) {
                float u[8];
                #pragma unroll
                for (int i = 0; i < 8; ++i) {
                    v2f a = hp0 * wi[i][0];
                    a += hp1 * wi[i][1];
                    a += hp2 * wi[i][2];
                    a += hp3 * wi[i][3];
                    u[i] = a.x + a.y;
                }
                const float xwn = red_scatter(u, r);
                if (r < 8) xwr[l][(s - 1) & 1][cc] = xwn;
            }

            if (do_stage) *(float4*)(&xwl[cb ^ 1][t][pos]) = stg;
        }
        __syncthreads();
    }

    // h_3(255) was written into hsw[3][0] at s=255
    if (l == 3 && t256 < 32) {
        const float4 hv = *(const float4*)(&hsw[3][0][12 * (t256 >> 1) + 4 * (t256 & 1)]);
        *(float4*)(hfin + (size_t)b * HH + 4 * t256) = hv;
    }
}

// =====================================================================
__global__ __launch_bounds__(128)
void fc_k(const float* __restrict__ hlast, const float* __restrict__ fc_w,
          const float* __restrict__ fc_b, float* __restrict__ out)
{
    const int b = blockIdx.x;
    const int tid = threadIdx.x;
    __shared__ __align__(16) float h[HH];
    h[tid] = hlast[(size_t)b * HH + tid];
    __syncthreads();
    if (tid < NC) {
        float a = fc_b[tid];
        const float* wr = fc_w + tid * HH;
        #pragma unroll 4
        for (int k = 0; k < HH; ++k) a += h[k] * wr[k];
        out[(size_t)b * NC + tid] = a;
    }
}

extern "C" void kernel_launch(void* const* d_in, const int* in_sizes, int n_in,
                              void* d_out, int out_size, void* d_ws, size_t ws_size,
                              hipStream_t stream) {
    const float* x     = (const float*)d_in[0];   // (512,256,28)
    const float* w_ih0 = (const float*)d_in[1];   // (128,28)
    const float* w_hh0 = (const float*)d_in[2];   // (128,128)
    const float* b_ih0 = (const float*)d_in[3];
    const float* b_hh0 = (const float*)d_in[4];
    const float* w_ih  = (const float*)d_in[5];   // (3,128,128)
    const float* w_hh  = (const float*)d_in[6];   // (3,128,128)
    const float* b_ih  = (const float*)d_in[7];   // (3,128)
    const float* b_hh  = (const float*)d_in[8];
    const float* fc_w  = (const float*)d_in[9];   // (10,128)
    const float* fc_b  = (const float*)d_in[10];
    float* out = (float*)d_out;

    float* buf  = (float*)d_ws;                   // (B,S,H) fp32 = 64 MB
    float* hfin = buf + (size_t)BB * SS * HH;     // (B,H)

    // layer 0 input projection (bias-free; scan adds bias)
    proj_k<28><<<(BB * SS) / 64, 256, 0, stream>>>(x, w_ih0, buf);
    // all 4 recurrent layers, wavefront-pipelined
    fused_scan<<<BB, 1024, 0, stream>>>(buf, hfin, w_hh0, w_hh, w_ih,
                                        b_ih0, b_hh0, b_ih, b_hh);
    fc_k<<<BB, 128, 0, stream>>>(hfin, fc_w, fc_b, out);
}

// Round 2
// 684.798 us; speedup vs baseline: 4.1061x; 4.1061x over previous
//
#include <hip/hip_runtime.h>

#define BB 512
#define SS 256
#define HH 128
#define NC 10

typedef float v2f __attribute__((ext_vector_type(2)));

// acc + (give from lane selected by DPP ctrl)
template<int CTRL>
__device__ __forceinline__ float dppadd(float acc, float give) {
    int t = __builtin_amdgcn_update_dpp(0, __float_as_int(give), CTRL, 0xF, 0xF, true);
    return acc + __int_as_float(t);
}

// cndmask-free reduce-scatter over the 16-lane group (verified).
// Input v[8] in permuted slot order (slot i = column 8j + (i^(r&7))).
// Returns full sum for column 8j + (r&7); copies at lanes r and r^8.
__device__ __forceinline__ float red_scatter(const float v[8], int r) {
    float s0 = dppadd<0xB1>(v[0], v[1]);    // xor1
    float s2 = dppadd<0xB1>(v[2], v[3]);
    float s4 = dppadd<0xB1>(v[4], v[5]);
    float s6 = dppadd<0xB1>(v[6], v[7]);
    s0 = dppadd<0x4E>(s0, s2);              // xor2
    s4 = dppadd<0x4E>(s4, s6);
    {   // xor4 via row_ror 4 / 12
        int t1 = __builtin_amdgcn_update_dpp(0, __float_as_int(s4), 0x124, 0xF, 0xF, true);
        int t2 = __builtin_amdgcn_update_dpp(0, __float_as_int(s4), 0x12C, 0xF, 0xF, true);
        s0 += __int_as_float((r & 4) ? t2 : t1);
    }
    s0 = dppadd<0x128>(s0, s0);             // xor8 (row_ror:8)
    return s0;
}

// =====================================================================
// proj_k: out[m][j] = sum_d A[m][d] * W[j][d]   (NO bias — scans add it)
// Layer 0 input projection only (K=28).
// =====================================================================
template<int K>
__global__ __launch_bounds__(256, 1)
void proj_k(const float* __restrict__ A, const float* __restrict__ W,
            float* __restrict__ out)
{
    constexpr int AS = ((K + 31) / 32) * 32 + 4;
    constexpr int KQ = K / 4;
    constexpr int KCW = (K < 32) ? K : 32;
    constexpr int WQ = KCW / 4;
    const int tid = threadIdx.x;
    const int tx = tid & 15;
    const int ty = tid >> 4;
    const size_t m0 = (size_t)blockIdx.x * 64;

    __shared__ float Arm[64 * AS];
    __shared__ float Wst[128 * 36];

    for (int idx = tid; idx < 64 * KQ; idx += 256) {
        const int row = idx / KQ, kq = idx % KQ;
        const float4 v = *(const float4*)(A + (m0 + row) * K + 4 * kq);
        *(float4*)(&Arm[row * AS + 4 * kq]) = v;
    }

    float acc[4][8];
    #pragma unroll
    for (int c = 0; c < 8; ++c)
        #pragma unroll
        for (int r = 0; r < 4; ++r) acc[r][c] = 0.f;

    #pragma unroll 1
    for (int kc = 0; kc < K; kc += KCW) {
        __syncthreads();
        for (int idx = tid; idx < 128 * WQ; idx += 256) {
            const int col = idx / WQ, q = idx % WQ;
            const float4 v = *(const float4*)(W + (size_t)col * K + kc + 4 * q);
            *(float4*)(&Wst[col * 36 + 4 * q]) = v;
        }
        __syncthreads();
        #pragma unroll 2
        for (int q = 0; q < WQ; ++q) {
            float4 av[4];
            #pragma unroll
            for (int r = 0; r < 4; ++r)
                av[r] = *(const float4*)(&Arm[(ty + 16 * r) * AS + kc + 4 * q]);
            #pragma unroll
            for (int c = 0; c < 8; ++c) {
                const float4 wv = *(const float4*)(&Wst[(tx + 16 * c) * 36 + 4 * q]);
                #pragma unroll
                for (int r = 0; r < 4; ++r)
                    acc[r][c] += av[r].x * wv.x + av[r].y * wv.y
                               + av[r].z * wv.z + av[r].w * wv.w;
            }
        }
    }

    #pragma unroll
    for (int r = 0; r < 4; ++r)
        #pragma unroll
        for (int c = 0; c < 8; ++c)
            out[(m0 + ty + 16 * r) * HH + tx + 16 * c] = acc[r][c];
}

// =====================================================================
// scan_split (non-last layers): 512 threads = 2 wave-groups of 256.
//   wg0 (recurrence, critical path):  h_s = tanh(bias + xw[s] + h_{s-1} W_hh^T)
//   wg1 (latency-tolerant):           xw_next[s-1] = h_{s-1} W_ih_next^T
//                                     + global->LDS staging of xw chunks
// Each thread holds ONE permuted weight matrix fragment (64 VGPRs) —
// half the register footprint of the old fused-per-thread scan_k, at
// 2x the occupancy (4 waves/SIMD). Both groups share the identical
// MAC + red_scatter body; only the epilogue of the step differs.
// In-place on buf: slice X read (staged) at step X-8, written at X+1.
// =====================================================================
__global__ __attribute__((amdgpu_flat_work_group_size(512, 512),
                          amdgpu_waves_per_eu(4, 4)))
void scan_split(float* __restrict__ buf,
                const float* __restrict__ w_hh, const float* __restrict__ w_ih_next,
                const float* __restrict__ b_ih_l, const float* __restrict__ b_hh_l)
{
    const int b    = blockIdx.x;
    const int tid  = threadIdx.x;
    const int wg   = tid >> 8;       // 0 = recurrence, 1 = projection+staging
    const int t256 = tid & 255;
    const int j   = t256 >> 4;       // col group: cols 8j..8j+7
    const int r   = t256 & 15;       // k-chunk [8r, 8r+8)
    const int g7  = r & 7;
    const int cc  = 8 * j + g7;      // column this lane finalizes
    const int wsw = 12 * j + g7;     // its swizzled LDS word

    float* const row = buf + (size_t)b * SS * HH;
    const float bias = b_ih_l[cc] + b_hh_l[cc];     // used by wg0 only

    // permuted weights: slot i = column 8j + (i^g7), k-pair p
    const float* wsrc = wg ? w_ih_next : w_hh;
    v2f w[8][4];
    #pragma unroll
    for (int i = 0; i < 8; ++i) {
        const v2f* p = (const v2f*)(wsrc + (size_t)(8 * j + (i ^ g7)) * HH + 8 * r);
        w[i][0] = p[0]; w[i][1] = p[1]; w[i][2] = p[2]; w[i][3] = p[3];
    }

    __shared__ float hsw[2][192];        // h[k] at word 12*(k>>3)+(k&7)
    __shared__ float xwl[2][8][HH];      // 8-step xw double buffer

    if (tid < 192) hsw[0][tid] = 0.f;
    const int t   = t256 >> 5;           // staging: step-in-chunk
    const int pos = (t256 & 31) * 4;     // staging: column (float4)
    if (wg == 1) {                       // stage xw for steps 0..7
        const float4 v = *(const float4*)(row + (size_t)t * HH + pos);
        *(float4*)(&xwl[0][t][pos]) = v;
    }
    __syncthreads();

    int cur = 0;
    for (int s = 0; s < SS; ++s) {
        const int ph = s & 7, cb = (s >> 3) & 1;
        const bool do_stage = (wg == 1) && (ph == 0) && (s + 8 < SS);
        float4 stg;
        if (do_stage)
            stg = *(const float4*)(row + (size_t)(s + 8 + t) * HH + pos);
        float myxw = 0.f;
        if (wg == 0) myxw = xwl[cb][ph][cc] + bias;

        // h_{s-1} fragments
        const v2f* hb = (const v2f*)&hsw[cur][12 * r];
        const v2f hp0 = hb[0], hp1 = hb[1], hp2 = hb[2], hp3 = hb[3];

        // shared MAC body (wg0: W_hh, wg1: W_ih_next)
        float v[8];
        #pragma unroll
        for (int i = 0; i < 8; ++i) {
            v2f a = hp0 * w[i][0];
            a += hp1 * w[i][1];
            a += hp2 * w[i][2];
            a += hp3 * w[i][3];
            v[i] = a.x + a.y;
        }
        const float res = red_scatter(v, r);

        if (wg == 0) {
            const float z = res + myxw;
            const float e = __expf(2.f * z);
            const float hnew = 1.f - 2.f * __builtin_amdgcn_rcpf(1.f + e);  // tanh(z)
            if (r < 8) hsw[cur ^ 1][wsw] = hnew;
        } else {
            if (s > 0 && r < 8) row[(size_t)(s - 1) * HH + cc] = res;
            if (do_stage) *(float4*)(&xwl[cb ^ 1][t][pos]) = stg;
        }
        __syncthreads();
        cur ^= 1;
    }

    // epilogue: project h_{SS-1} (lives in hsw[cur])
    if (wg == 1) {
        const v2f* hb = (const v2f*)&hsw[cur][12 * r];
        const v2f hp0 = hb[0], hp1 = hb[1], hp2 = hb[2], hp3 = hb[3];
        float u[8];
        #pragma unroll
        for (int i = 0; i < 8; ++i) {
            v2f a = hp0 * w[i][0];
            a += hp1 * w[i][1];
            a += hp2 * w[i][2];
            a += hp3 * w[i][3];
            u[i] = a.x + a.y;
        }
        const float xwn = red_scatter(u, r);
        if (r < 8) row[(size_t)(SS - 1) * HH + cc] = xwn;
    }
}

// =====================================================================
// scan_k<true>: LAST layer only — recurrence + final-h writeback.
// (Proven round-0 kernel, 256 threads, 2 waves/EU.)
// =====================================================================
template<bool LAST>
__global__ __attribute__((amdgpu_flat_work_group_size(256, 256),
                          amdgpu_waves_per_eu(2, 2)))
void scan_k(float* __restrict__ buf, float* __restrict__ hfin,
            const float* __restrict__ w_hh,
            const float* __restrict__ b_ih_l, const float* __restrict__ b_hh_l)
{
    const int b   = blockIdx.x;
    const int tid = threadIdx.x;
    const int j   = tid >> 4;
    const int r   = tid & 15;
    const int g7  = r & 7;

    float* const row = buf + (size_t)b * SS * HH;
    const int cc  = 8 * j + g7;
    const int wsw = 12 * j + g7;
    const float bias = b_ih_l[cc] + b_hh_l[cc];

    v2f wh[8][4];
    #pragma unroll
    for (int i = 0; i < 8; ++i) {
        const v2f* p = (const v2f*)(w_hh + (size_t)(8 * j + (i ^ g7)) * HH + 8 * r);
        wh[i][0] = p[0]; wh[i][1] = p[1]; wh[i][2] = p[2]; wh[i][3] = p[3];
    }

    __shared__ float hsw[2][192];
    __shared__ float xwl[2][8][HH];

    if (tid < 192) hsw[0][tid] = 0.f;
    const int t   = tid >> 5;
    const int pos = (tid & 31) * 4;
    {
        const float4 v = *(const float4*)(row + (size_t)t * HH + pos);
        *(float4*)(&xwl[0][t][pos]) = v;
    }
    __syncthreads();

    int cur = 0;
    for (int s = 0; s < SS; ++s) {
        const int ph = s & 7, cb = (s >> 3) & 1;
        const bool do_stage = (ph == 0) && (s + 8 < SS);
        float4 stg;
        if (do_stage)
            stg = *(const float4*)(row + (size_t)(s + 8 + t) * HH + pos);
        const float myxw = xwl[cb][ph][cc] + bias;

        const v2f* hb = (const v2f*)&hsw[cur][12 * r];
        const v2f hp0 = hb[0], hp1 = hb[1], hp2 = hb[2], hp3 = hb[3];

        float v[8];
        #pragma unroll
        for (int i = 0; i < 8; ++i) {
            v2f a = hp0 * wh[i][0];
            a += hp1 * wh[i][1];
            a += hp2 * wh[i][2];
            a += hp3 * wh[i][3];
            v[i] = a.x + a.y;
        }
        const float z = red_scatter(v, r) + myxw;
        const float e = __expf(2.f * z);
        const float hnew = 1.f - 2.f * __builtin_amdgcn_rcpf(1.f + e);  // tanh(z)
        if (r < 8) hsw[cur ^ 1][wsw] = hnew;

        if (do_stage) *(float4*)(&xwl[cb ^ 1][t][pos]) = stg;
        __syncthreads();
        cur ^= 1;
    }

    if (tid < 32) {
        const float4 hv = *(const float4*)(&hsw[cur][12 * (tid >> 1) + 4 * (tid & 1)]);
        *(float4*)(hfin + (size_t)b * HH + 4 * tid) = hv;
    }
}

// =====================================================================
__global__ __launch_bounds__(128)
void fc_k(const float* __restrict__ hlast, const float* __restrict__ fc_w,
          const float* __restrict__ fc_b, float* __restrict__ out)
{
    const int b = blockIdx.x;
    const int tid = threadIdx.x;
    __shared__ __align__(16) float h[HH];
    h[tid] = hlast[(size_t)b * HH + tid];
    __syncthreads();
    if (tid < NC) {
        float a = fc_b[tid];
        const float* wr = fc_w + tid * HH;
        #pragma unroll 4
        for (int k = 0; k < HH; ++k) a += h[k] * wr[k];
        out[(size_t)b * NC + tid] = a;
    }
}

extern "C" void kernel_launch(void* const* d_in, const int* in_sizes, int n_in,
                              void* d_out, int out_size, void* d_ws, size_t ws_size,
                              hipStream_t stream) {
    const float* x     = (const float*)d_in[0];   // (512,256,28)
    const float* w_ih0 = (const float*)d_in[1];   // (128,28)
    const float* w_hh0 = (const float*)d_in[2];   // (128,128)
    const float* b_ih0 = (const float*)d_in[3];
    const float* b_hh0 = (const float*)d_in[4];
    const float* w_ih  = (const float*)d_in[5];   // (3,128,128)
    const float* w_hh  = (const float*)d_in[6];   // (3,128,128)
    const float* b_ih  = (const float*)d_in[7];   // (3,128)
    const float* b_hh  = (const float*)d_in[8];
    const float* fc_w  = (const float*)d_in[9];   // (10,128)
    const float* fc_b  = (const float*)d_in[10];
    float* out = (float*)d_out;

    float* buf  = (float*)d_ws;                   // (B,S,H) fp32 = 64 MB
    float* hfin = buf + (size_t)BB * SS * HH;     // (B,H)

    // layer 0 input projection (bias-free; scan adds bias)
    proj_k<28><<<(BB * SS) / 64, 256, 0, stream>>>(x, w_ih0, buf);
    // layers 0..2: recurrence waves + projection waves (next layer's xw)
    scan_split<<<BB, 512, 0, stream>>>(buf, w_hh0, w_ih, b_ih0, b_hh0);
    scan_split<<<BB, 512, 0, stream>>>(buf, w_hh,
                                       w_ih + (size_t)1 * HH * HH, b_ih, b_hh);
    scan_split<<<BB, 512, 0, stream>>>(buf, w_hh + (size_t)1 * HH * HH,
                                       w_ih + (size_t)2 * HH * HH,
                                       b_ih + HH, b_hh + HH);
    // layer 3 (LAST): recurrence only, writes final h
    scan_k<true><<<BB, 256, 0, stream>>>(buf, hfin, w_hh + (size_t)2 * HH * HH,
                                         b_ih + 2 * HH, b_hh + 2 * HH);
    fc_k<<<BB, 128, 0, stream>>>(hfin, fc_w, fc_b, out);
}